// Round 14
// baseline (594.884 us; speedup 1.0000x reference)
//
#include <hip/hip_runtime.h>
#include <stdint.h>

// Problem constants
#define Bb 8
#define Ss 2048
#define Dd 512
#define Hh 8
#define Ee 64
#define Oo 512
#define Ff 512    // H*E
#define Ncat 1536 // 3*H*E fused QKV output columns

typedef _Float16 half_t;
typedef __attribute__((ext_vector_type(8))) _Float16 f16x8;   // 8 fp16 (4 VGPRs)
typedef __attribute__((ext_vector_type(4))) float f32x4;      // 16x16 MFMA acc
typedef __attribute__((ext_vector_type(16))) float f32x16;    // 32x32 MFMA acc
typedef __attribute__((ext_vector_type(4))) float f4;
typedef __attribute__((ext_vector_type(4))) half_t h16x4;
typedef __attribute__((ext_vector_type(4))) unsigned int u32x4;

__device__ __forceinline__ float exp2_fast(float x) {
    float r; asm("v_exp_f32 %0, %1" : "=v"(r) : "v"(x)); return r;  // HW 2^x
}
__device__ __forceinline__ f32x16 zero16() {
    f32x16 z;
#pragma unroll
    for (int i = 0; i < 16; ++i) z[i] = 0.f;
    return z;
}
// async global->LDS, 16B per lane; LDS dest is wave-uniform base + lane*16 (HW)
__device__ __forceinline__ void gload16(const half_t* g, half_t* l) {
    __builtin_amdgcn_global_load_lds(
        (const __attribute__((address_space(1))) void*)g,
        (__attribute__((address_space(3))) void*)l, 16, 0, 0);
}

// ---------------- query f32 -> f16, chunk-swizzled (c ^= s&7 within 64-el groups) -----
__global__ __launch_bounds__(256) void k_cvt_x(const float* __restrict__ x,
                                               half_t* __restrict__ xh) {
    int t = blockIdx.x * 256 + threadIdx.x;
    int s = t >> 6, c = t & 63;
    int cg = c >> 3, cl = c & 7;
    const float* src = x + (size_t)s * Dd + c * 8;
    f4 v0 = *(const f4*)src;
    f4 v1 = *(const f4*)(src + 4);
    union { half_t h[8]; u32x4 u; } o;
#pragma unroll
    for (int j = 0; j < 4; ++j) { o.h[j] = (half_t)v0[j]; o.h[4 + j] = (half_t)v1[j]; }
    int cd = cg * 8 + (cl ^ (s & 7));
    *(u32x4*)(xh + (size_t)s * Dd + cd * 8) = o.u;
}

// -------- weights: Wcat[n][d] (n = sel*512 + h*64 + e), WoT[o][f]; both chunk-swizzled --
__global__ __launch_bounds__(256) void k_cvt_w(const float* __restrict__ Wq, const float* __restrict__ Wk,
                                               const float* __restrict__ Wv, const float* __restrict__ Wo,
                                               half_t* __restrict__ Wcat, half_t* __restrict__ WoT) {
    int t = blockIdx.x * 256 + threadIdx.x;            // 0 .. 131071
    union { half_t h[8]; u32x4 u; } o;
    if (t < Ncat * 64) {                               // Wcat: n-row chunks
        int n = t >> 6, dc = t & 63;
        int sel = n >> 9, h = (n >> 6) & 7, e = n & 63;
        const float* W = (sel == 0) ? Wq : (sel == 1) ? Wk : Wv;
        const float* src = W + ((size_t)h * Dd + dc * 8) * Ee + e;   // W[h][d][e], stride Ee over d
#pragma unroll
        for (int j = 0; j < 8; ++j) o.h[j] = (half_t)src[(size_t)j * Ee];
        int dcs = (dc & ~7) | ((dc & 7) ^ (n & 7));
        *(u32x4*)(Wcat + (size_t)n * Dd + dcs * 8) = o.u;
    } else {                                           // WoT: o-row chunks
        int u2 = t - Ncat * 64;
        int oo = u2 >> 6, fc = u2 & 63;
        const float* src = Wo + (size_t)(fc * 8) * Oo + oo;          // Wo[f][o], stride Oo over f
#pragma unroll
        for (int j = 0; j < 8; ++j) o.h[j] = (half_t)src[(size_t)j * Oo];
        int fcs = (fc & ~7) | ((fc & 7) ^ (oo & 7));
        *(u32x4*)(WoT + (size_t)oo * Ff + fcs * 8) = o.u;
    }
}

// ---------------- fused QKV: one GEMM C[16384,1536] = X * Wcat^T (2-phase gload_lds) ----
__global__ __launch_bounds__(256, 2) void k_qkv(const half_t* __restrict__ A,    // xh (swizzled)
                                                const half_t* __restrict__ Bw,   // Wcat (swizzled)
                                                half_t* __restrict__ Q,
                                                half_t* __restrict__ K,
                                                half_t* __restrict__ Vt) {
    __shared__ __attribute__((aligned(16))) half_t Ab[2][128 * 64];
    __shared__ __attribute__((aligned(16))) half_t Bbuf[2][128 * 64];

    int bid = blockIdx.x;
    int virt = (bid & 7) * 192 + (bid >> 3);           // XCD x owns virt [x*192, x*192+192)
    int bm = virt / 12, bn = virt % 12;
    int m0 = bm * 128, n0 = bn * 128;

    int wave = threadIdx.x >> 6, lane = threadIdx.x & 63;
    int ar = lane & 15, kg = lane >> 4;
    int wm = wave >> 1, wn = wave & 1;
    int lr = lane >> 3, lc = lane & 7;                 // staging: row-in-seg, chunk

    f32x4 acc[4][4];
#pragma unroll
    for (int i = 0; i < 4; ++i)
#pragma unroll
        for (int j = 0; j < 4; ++j) acc[i][j] = (f32x4){0, 0, 0, 0};

#define STAGE_QKV(buf, kt)                                                              \
    {                                                                                   \
        _Pragma("unroll")                                                               \
        for (int i = 0; i < 4; ++i) {                                                   \
            int seg = wave * 4 + i;                                                     \
            int row = seg * 8 + lr;                                                     \
            gload16(A  + (size_t)(m0 + row) * Dd + (kt) * 64 + lc * 8, &Ab[buf][seg * 512]);   \
            gload16(Bw + (size_t)(n0 + row) * Dd + (kt) * 64 + lc * 8, &Bbuf[buf][seg * 512]); \
        }                                                                               \
    }

    STAGE_QKV(0, 0);
    __syncthreads();
    int cur = 0;
    for (int kt = 0; kt < 8; ++kt) {
        if (kt < 7) STAGE_QKV(cur ^ 1, kt + 1);
        f16x8 bf[4][2];
#pragma unroll
        for (int n = 0; n < 4; ++n) {
            int row = wn * 64 + n * 16 + ar;
#pragma unroll
            for (int kh = 0; kh < 2; ++kh)
                bf[n][kh] = *(const f16x8*)&Bbuf[cur][row * 64 + (((kg + kh * 4)) ^ (row & 7)) * 8];
        }
#pragma unroll
        for (int mi = 0; mi < 4; ++mi) {
            int row = wm * 64 + mi * 16 + ar;
            f16x8 a0 = *(const f16x8*)&Ab[cur][row * 64 + ((kg)     ^ (row & 7)) * 8];
            f16x8 a1 = *(const f16x8*)&Ab[cur][row * 64 + ((kg + 4) ^ (row & 7)) * 8];
#pragma unroll
            for (int n = 0; n < 4; ++n) {
                acc[mi][n] = __builtin_amdgcn_mfma_f32_16x16x32_f16(a0, bf[n][0], acc[mi][n], 0, 0, 0);
                acc[mi][n] = __builtin_amdgcn_mfma_f32_16x16x32_f16(a1, bf[n][1], acc[mi][n], 0, 0, 0);
            }
        }
        __syncthreads();
        cur ^= 1;
    }
    // epilogue: sel is block-uniform (N tiled 4/4/4 over Q,K,V)
    int sel = n0 >> 9;
#pragma unroll
    for (int sn = 0; sn < 4; ++sn) {
        int nb = n0 + wn * 64 + sn * 16;
        int h = (nb >> 6) & 7, eb = nb & 63;
#pragma unroll
        for (int mi = 0; mi < 4; ++mi)
#pragma unroll
            for (int r = 0; r < 4; ++r) {
                int sg = m0 + wm * 64 + mi * 16 + kg * 4 + r;
                int bh = (sg >> 11) * 8 + h, sl = sg & 2047;
                half_t val = (half_t)acc[mi][sn][r];
                if (sel == 0)      Q [((size_t)bh * Ss + sl) * Ee + eb + ar] = val;
                else if (sel == 1) K [((size_t)bh * Ss + sl) * Ee + eb + ar] = val;
                else               Vt[((size_t)bh * Ee + eb + ar) * Ss + sl] = val;
            }
    }
#undef STAGE_QKV
}

// ---------------- flash attention: swapped 32x32, kt-SPLIT 8-wave blocks ----------------
// 1024 blocks x 512 thr. Waves 0-3 (lo): q-tiles qb*4+w over kt32 [0, 2qb+2);
// waves 4-7 (hi): SAME q-tiles over kt32 [2qb+2, 4qb+4). Equal trips T=2qb+2 ->
// one unconditional barrier/iter. Two independent KVBLK=32 dbuf streams (32 KB);
// in-block merge of (O, m, lp) partials via LDS overlay. 4 blocks/CU = 32 waves/CU.
__global__ __launch_bounds__(512, 8) void k_attn(const half_t* __restrict__ Q,
                                                 const half_t* __restrict__ Kg,
                                                 const half_t* __restrict__ Vtg,
                                                 half_t* __restrict__ ctx) {
    // staging: 4 regions (grp,buf) x (K 2048 + V 2048 halfs) = 32 KB.
    // merge overlay (after final barrier): 4 waves x 64 lanes x 34 f32 = 34816 B.
    __shared__ __attribute__((aligned(16))) char smem[35072];
    half_t* stg = (half_t*)smem;
    float*  mrg = (float*)smem;

    int bid = blockIdx.x;                 // 0..1023
    int xcd = bid & 7;
    int idx = bid >> 3;                   // 0..127
    int g   = idx >> 3;                   // 0..15
    int g0 = g & 3, j = g >> 2;           // balanced qb permutation (per-CU sums 30)
    int qb;
    switch (j) {
        case 0:  qb = 15 - g0; break;
        case 1:  qb = 8 + (g0 ^ 2); break;
        case 2:  qb = 4 + g0; break;
        default: qb = g0 ^ 1; break;
    }
    int bh = xcd * 8 + (idx & 7);         // 8 heads per XCD

    int wave = threadIdx.x >> 6, lane = threadIdx.x & 63;
    int grp = wave >> 2, w4 = wave & 3;   // grp 0 = lo ktrange, 1 = hi
    int ql = lane & 31, hi = lane >> 5;
    int qt32 = qb * 4 + w4;
    int qg = qt32 * 32 + ql;

    const half_t* Qb = Q   + (size_t)bh * Ss * Ee;
    const half_t* Kb = Kg  + (size_t)bh * Ss * Ee;
    const half_t* Vb = Vtg + (size_t)bh * Ee * Ss;

    // Q B-frags (persistent), pre-scaled by log2(e)
    const half_t* qp = Qb + (size_t)qg * Ee + hi * 8;
    f16x8 qf[4];
    const half_t l2e = (half_t)1.44269504f;
#pragma unroll
    for (int d = 0; d < 4; ++d) {
        qf[d] = *(const f16x8*)(qp + d * 16);
#pragma unroll
        for (int jj = 0; jj < 8; ++jj) qf[d][jj] *= l2e;
    }

    f32x16 ot0 = zero16(), ot1 = zero16();
    float m = -1e30f, lp = 0.f;

    int SL = qb * 2 + 2;                  // hi stream start tile; also trips per group
    int tbase = grp * SL;
    half_t* reg0 = stg + (grp * 2 + 0) * 4096;   // my stream, buf 0 (K at +0, V at +2048)
    half_t* reg1 = stg + (grp * 2 + 1) * 4096;   // my stream, buf 1
    int sgb = w4 * 2;                     // this thread stages segs sgb, sgb+1

    // K seg s (0..3): lane l <- K[tile*32 + (l&31)][s*16 + (l>>5)*8 ..]
    // V seg s2 (0..3) = (eh<<1)|d2: lane l <- Vt[eh*32 + (l&31)][tile*32 + d2*16 + (l>>5)*8 ..]
#define STAGE_KV(buf, tile)                                                               \
    {                                                                                     \
        half_t* rg = (buf) ? reg1 : reg0;                                                 \
        _Pragma("unroll")                                                                 \
        for (int c = 0; c < 2; ++c) {                                                     \
            int s = sgb + c;                                                              \
            if (s < 4) {                                                                  \
                gload16(Kb + ((size_t)(tile) * 32 + ql) * Ee + s * 16 + hi * 8,           \
                        rg + s * 512);                                                    \
            } else {                                                                      \
                int s2 = s - 4, eh = s2 >> 1, d2 = s2 & 1;                                \
                gload16(Vb + (size_t)(eh * 32 + ql) * Ss + (tile) * 32 + d2 * 16 + hi * 8,\
                        rg + 2048 + s2 * 512);                                            \
            }                                                                             \
        }                                                                                 \
    }

    STAGE_KV(0, tbase);
    int cur = 0;
    for (int t = 0; t < SL; ++t) {
        __syncthreads();   // staged tile visible; prior reads of buf cur^1 done (all 8 waves)
        if (t + 1 < SL) STAGE_KV(cur ^ 1, tbase + t + 1);
        int kt32 = tbase + t;
        if (kt32 <= qt32) {
            half_t* rg = cur ? reg1 : reg0;
            // K fragments: conflict-free ds_read_b128
            f16x8 kf0 = *(const f16x8*)(rg + lane * 8);
            f16x8 kf1 = *(const f16x8*)(rg + 512 + lane * 8);
            f16x8 kf2 = *(const f16x8*)(rg + 1024 + lane * 8);
            f16x8 kf3 = *(const f16x8*)(rg + 1536 + lane * 8);

            f32x16 s = zero16();
            __builtin_amdgcn_s_setprio(1);
            s = __builtin_amdgcn_mfma_f32_32x32x16_f16(kf0, qf[0], s, 0, 0, 0);
            s = __builtin_amdgcn_mfma_f32_32x32x16_f16(kf1, qf[1], s, 0, 0, 0);
            s = __builtin_amdgcn_mfma_f32_32x32x16_f16(kf2, qf[2], s, 0, 0, 0);
            s = __builtin_amdgcn_mfma_f32_32x32x16_f16(kf3, qf[3], s, 0, 0, 0);
            __builtin_amdgcn_s_setprio(0);

            if (kt32 == qt32) {  // causal mask on the diagonal tile
#pragma unroll
                for (int r = 0; r < 16; ++r) {
                    int kloc = (r & 3) + 8 * (r >> 2) + 4 * hi;
                    if (kloc > ql) s[r] = -1e30f;
                }
            }

            // tree max over own 16, partner via shfl_xor(32)
            float m0a = fmaxf(s[0], s[1]),  m1a = fmaxf(s[2], s[3]);
            float m2a = fmaxf(s[4], s[5]),  m3a = fmaxf(s[6], s[7]);
            float m4a = fmaxf(s[8], s[9]),  m5a = fmaxf(s[10], s[11]);
            float m6a = fmaxf(s[12], s[13]), m7a = fmaxf(s[14], s[15]);
            float mt = fmaxf(fmaxf(fmaxf(m0a, m1a), fmaxf(m2a, m3a)),
                             fmaxf(fmaxf(m4a, m5a), fmaxf(m6a, m7a)));
            mt = fmaxf(mt, __shfl_xor(mt, 32));
            if (!__all(mt <= m + 8.0f)) {      // T13 defer-max
                float mn = fmaxf(m, mt);
                float sc = exp2_fast(m - mn);
#pragma unroll
                for (int r = 0; r < 16; ++r) { ot0[r] *= sc; ot1[r] *= sc; }
                lp *= sc;
                m = mn;
            }
            float rs = 0.f;
#pragma unroll
            for (int r = 0; r < 16; ++r) { s[r] = exp2_fast(s[r] - m); rs += s[r]; }
            lp += rs;

            // pack P to f16; partner halves via shfl_xor(32)
            unsigned w[8];
#pragma unroll
            for (int mm = 0; mm < 8; ++mm)
                asm("v_cvt_pkrtz_f16_f32 %0, %1, %2" : "=v"(w[mm]) : "v"(s[2 * mm]), "v"(s[2 * mm + 1]));
            unsigned t0 = (unsigned)__shfl_xor((int)(hi ? w[0] : w[2]), 32);
            unsigned t1 = (unsigned)__shfl_xor((int)(hi ? w[1] : w[3]), 32);
            unsigned t2 = (unsigned)__shfl_xor((int)(hi ? w[4] : w[6]), 32);
            unsigned t3 = (unsigned)__shfl_xor((int)(hi ? w[5] : w[7]), 32);
            union { unsigned u[4]; f16x8 v; } pb0, pb1;
            pb0.u[0] = hi ? t0 : w[0];  pb0.u[1] = hi ? t1 : w[1];
            pb0.u[2] = hi ? w[2] : t0;  pb0.u[3] = hi ? w[3] : t1;
            pb1.u[0] = hi ? t2 : w[4];  pb1.u[1] = hi ? t3 : w[5];
            pb1.u[2] = hi ? w[6] : t2;  pb1.u[3] = hi ? w[7] : t3;

            // V^T fragments: conflict-free
            f16x8 va0 = *(const f16x8*)(rg + 2048 + lane * 8);
            f16x8 va1 = *(const f16x8*)(rg + 2560 + lane * 8);
            f16x8 va2 = *(const f16x8*)(rg + 3072 + lane * 8);
            f16x8 va3 = *(const f16x8*)(rg + 3584 + lane * 8);

            __builtin_amdgcn_s_setprio(1);
            ot0 = __builtin_amdgcn_mfma_f32_32x32x16_f16(va0, pb0.v, ot0, 0, 0, 0);
            ot0 = __builtin_amdgcn_mfma_f32_32x32x16_f16(va1, pb1.v, ot0, 0, 0, 0);
            ot1 = __builtin_amdgcn_mfma_f32_32x32x16_f16(va2, pb0.v, ot1, 0, 0, 0);
            ot1 = __builtin_amdgcn_mfma_f32_32x32x16_f16(va3, pb1.v, ot1, 0, 0, 0);
            __builtin_amdgcn_s_setprio(0);
        }
        cur ^= 1;
    }
#undef STAGE_KV

    // ---- in-block merge of kt-split partials ----
    __syncthreads();   // all staging reads done; safe to overlay merge region
    if (grp) {         // hi waves publish partials
        float* p = mrg + ((size_t)(w4 * 64 + lane)) * 34;
#pragma unroll
        for (int r = 0; r < 16; ++r) { p[r] = ot0[r]; p[16 + r] = ot1[r]; }
        p[32] = m; p[33] = lp;
    }
    __syncthreads();
    if (!grp) {        // lo waves merge + normalize + store
        float* p = mrg + ((size_t)(w4 * 64 + lane)) * 34;
        float m2 = p[32], lp2 = p[33];
        float mn = fmaxf(m, m2);
        float sA = exp2_fast(m - mn);
        float sB = exp2_fast(m2 - mn);
        float lpm = lp * sA + lp2 * sB;
        float lf = lpm + __shfl_xor(lpm, 32);
        float inv = 1.0f / lf;
        int b = bh >> 3, h = bh & 7;
        int qs = qg & 7;
        half_t* cb = ctx + ((size_t)b * Ss + qg) * Ff;
#pragma unroll
        for (int gg = 0; gg < 4; ++gg) {
            h16x4 v0, v1;
#pragma unroll
            for (int jj = 0; jj < 4; ++jj) {
                float o0 = ot0[gg * 4 + jj] * sA + p[gg * 4 + jj] * sB;
                float o1 = ot1[gg * 4 + jj] * sA + p[16 + gg * 4 + jj] * sB;
                v0[jj] = (half_t)(o0 * inv);
                v1[jj] = (half_t)(o1 * inv);
            }
            *(h16x4*)(cb + (h * 8 + (gg ^ qs)) * 8 + 4 * hi)       = v0;
            *(h16x4*)(cb + (h * 8 + ((gg + 4) ^ qs)) * 8 + 4 * hi) = v1;
        }
    }
}

// ---------------- output projection: same 2-phase GEMM, C[16384,512] f32 ----------------
__global__ __launch_bounds__(256, 2) void k_proj(const half_t* __restrict__ A,    // ctx (swizzled)
                                                 const half_t* __restrict__ Bw,   // WoT (swizzled)
                                                 float* __restrict__ out) {
    __shared__ __attribute__((aligned(16))) half_t Ab[2][128 * 64];
    __shared__ __attribute__((aligned(16))) half_t Bbuf[2][128 * 64];

    int bid = blockIdx.x;
    int virt = (bid & 7) * 64 + (bid >> 3);
    int bm = virt >> 2, bn = virt & 3;
    int m0 = bm * 128, n0 = bn * 128;

    int wave = threadIdx.x >> 6, lane = threadIdx.x & 63;
    int ar = lane & 15, kg = lane >> 4;
    int wm = wave >> 1, wn = wave & 1;
    int lr = lane >> 3, lc = lane & 7;

    f32x4 acc[4][4];
#pragma unroll
    for (int i = 0; i < 4; ++i)
#pragma unroll
        for (int j = 0; j < 4; ++j) acc[i][j] = (f32x4){0, 0, 0, 0};

#define STAGE_PRJ(buf, kt)                                                              \
    {                                                                                   \
        _Pragma("unroll")                                                               \
        for (int i = 0; i < 4; ++i) {                                                   \
            int seg = wave * 4 + i;                                                     \
            int row = seg * 8 + lr;                                                     \
            gload16(A  + (size_t)(m0 + row) * Ff + (kt) * 64 + lc * 8, &Ab[buf][seg * 512]);   \
            gload16(Bw + (size_t)(n0 + row) * Ff + (kt) * 64 + lc * 8, &Bbuf[buf][seg * 512]); \
        }                                                                               \
    }

    STAGE_PRJ(0, 0);
    __syncthreads();
    int cur = 0;
    for (int kt = 0; kt < 8; ++kt) {
        if (kt < 7) STAGE_PRJ(cur ^ 1, kt + 1);
        f16x8 bf[4][2];
#pragma unroll
        for (int n = 0; n < 4; ++n) {
            int row = wn * 64 + n * 16 + ar;
#pragma unroll
            for (int kh = 0; kh < 2; ++kh)
                bf[n][kh] = *(const f16x8*)&Bbuf[cur][row * 64 + (((kg + kh * 4)) ^ (row & 7)) * 8];
        }
#pragma unroll
        for (int mi = 0; mi < 4; ++mi) {
            int row = wm * 64 + mi * 16 + ar;
            f16x8 a0 = *(const f16x8*)&Ab[cur][row * 64 + ((kg)     ^ (row & 7)) * 8];
            f16x8 a1 = *(const f16x8*)&Ab[cur][row * 64 + ((kg + 4) ^ (row & 7)) * 8];
#pragma unroll
            for (int n = 0; n < 4; ++n) {
                acc[mi][n] = __builtin_amdgcn_mfma_f32_16x16x32_f16(a0, bf[n][0], acc[mi][n], 0, 0, 0);
                acc[mi][n] = __builtin_amdgcn_mfma_f32_16x16x32_f16(a1, bf[n][1], acc[mi][n], 0, 0, 0);
            }
        }
        __syncthreads();
        cur ^= 1;
    }
#pragma unroll
    for (int sn = 0; sn < 4; ++sn)
#pragma unroll
        for (int mi = 0; mi < 4; ++mi)
#pragma unroll
            for (int r = 0; r < 4; ++r) {
                int sg = m0 + wm * 64 + mi * 16 + kg * 4 + r;
                out[(size_t)sg * Oo + n0 + wn * 64 + sn * 16 + ar] = acc[mi][sn][r];
            }
#undef STAGE_PRJ
}

extern "C" void kernel_launch(void* const* d_in, const int* in_sizes, int n_in,
                              void* d_out, int out_size, void* d_ws, size_t ws_size,
                              hipStream_t stream) {
    const float* x  = (const float*)d_in[0];
    const float* Wq = (const float*)d_in[1];
    const float* Wk = (const float*)d_in[2];
    const float* Wv = (const float*)d_in[3];
    const float* Wo = (const float*)d_in[4];
    float* out = (float*)d_out;

    // workspace (all f16, fully rewritten every call): ~82 MB
    char* ws = (char*)d_ws;
    size_t off = 0;
    half_t* xh   = (half_t*)(ws + off); off += (size_t)Bb * Ss * Dd * 2;      // swizzled
    half_t* Wcat = (half_t*)(ws + off); off += (size_t)Ncat * Dd * 2;         // swizzled
    half_t* WoT  = (half_t*)(ws + off); off += (size_t)Oo * Ff * 2;           // swizzled
    half_t* Qd   = (half_t*)(ws + off); off += (size_t)Bb * Hh * Ss * Ee * 2; // plain [bh][s][e]
    half_t* Kd   = (half_t*)(ws + off); off += (size_t)Bb * Hh * Ss * Ee * 2; // plain [bh][s][e]
    half_t* Vtd  = (half_t*)(ws + off); off += (size_t)Bb * Hh * Ss * Ee * 2; // plain [bh][e][s]
    half_t* ctx  = (half_t*)(ws + off); off += (size_t)Bb * Ss * Ff * 2;      // swizzled

    k_cvt_x<<<4096, 256, 0, stream>>>(x, xh);
    k_cvt_w<<<512, 256, 0, stream>>>(Wq, Wk, Wv, Wo, Wcat, WoT);
    k_qkv<<<1536, 256, 0, stream>>>(xh, Wcat, Qd, Kd, Vtd);
    k_attn<<<1024, 512, 0, stream>>>(Qd, Kd, Vtd, ctx);
    k_proj<<<512, 256, 0, stream>>>(ctx, WoT, out);
}

// Round 16
// 130.466 us; speedup vs baseline: 4.5597x; 4.5597x over previous
//
#include <hip/hip_runtime.h>
#include <stdint.h>

// Problem constants
#define Bb 8
#define Ss 2048
#define Dd 512
#define Hh 8
#define Ee 64
#define Oo 512
#define Ff 512    // H*E
#define Ncat 1536 // 3*H*E fused QKV output columns

typedef _Float16 half_t;
typedef __attribute__((ext_vector_type(8))) _Float16 f16x8;   // 8 fp16 (4 VGPRs)
typedef __attribute__((ext_vector_type(4))) float f32x4;      // 16x16 MFMA acc
typedef __attribute__((ext_vector_type(16))) float f32x16;    // 32x32 MFMA acc
typedef __attribute__((ext_vector_type(4))) float f4;
typedef __attribute__((ext_vector_type(4))) half_t h16x4;
typedef __attribute__((ext_vector_type(4))) unsigned int u32x4;

__device__ __forceinline__ float exp2_fast(float x) {
    float r; asm("v_exp_f32 %0, %1" : "=v"(r) : "v"(x)); return r;  // HW 2^x
}
__device__ __forceinline__ f32x16 zero16() {
    f32x16 z;
#pragma unroll
    for (int i = 0; i < 16; ++i) z[i] = 0.f;
    return z;
}
// async global->LDS, 16B per lane; LDS dest is wave-uniform base + lane*16 (HW)
__device__ __forceinline__ void gload16(const half_t* g, half_t* l) {
    __builtin_amdgcn_global_load_lds(
        (const __attribute__((address_space(1))) void*)g,
        (__attribute__((address_space(3))) void*)l, 16, 0, 0);
}

// ---------------- query f32 -> f16, chunk-swizzled (c ^= s&7 within 64-el groups) -----
__global__ __launch_bounds__(256) void k_cvt_x(const float* __restrict__ x,
                                               half_t* __restrict__ xh) {
    int t = blockIdx.x * 256 + threadIdx.x;
    int s = t >> 6, c = t & 63;
    int cg = c >> 3, cl = c & 7;
    const float* src = x + (size_t)s * Dd + c * 8;
    f4 v0 = *(const f4*)src;
    f4 v1 = *(const f4*)(src + 4);
    union { half_t h[8]; u32x4 u; } o;
#pragma unroll
    for (int j = 0; j < 4; ++j) { o.h[j] = (half_t)v0[j]; o.h[4 + j] = (half_t)v1[j]; }
    int cd = cg * 8 + (cl ^ (s & 7));
    *(u32x4*)(xh + (size_t)s * Dd + cd * 8) = o.u;
}

// -------- weights: Wcat[n][d] (n = sel*512 + h*64 + e), WoT[o][f]; both chunk-swizzled --
__global__ __launch_bounds__(256) void k_cvt_w(const float* __restrict__ Wq, const float* __restrict__ Wk,
                                               const float* __restrict__ Wv, const float* __restrict__ Wo,
                                               half_t* __restrict__ Wcat, half_t* __restrict__ WoT) {
    int t = blockIdx.x * 256 + threadIdx.x;            // 0 .. 131071
    union { half_t h[8]; u32x4 u; } o;
    if (t < Ncat * 64) {                               // Wcat: n-row chunks
        int n = t >> 6, dc = t & 63;
        int sel = n >> 9, h = (n >> 6) & 7, e = n & 63;
        const float* W = (sel == 0) ? Wq : (sel == 1) ? Wk : Wv;
        const float* src = W + ((size_t)h * Dd + dc * 8) * Ee + e;   // W[h][d][e], stride Ee over d
#pragma unroll
        for (int j = 0; j < 8; ++j) o.h[j] = (half_t)src[(size_t)j * Ee];
        int dcs = (dc & ~7) | ((dc & 7) ^ (n & 7));
        *(u32x4*)(Wcat + (size_t)n * Dd + dcs * 8) = o.u;
    } else {                                           // WoT: o-row chunks
        int u2 = t - Ncat * 64;
        int oo = u2 >> 6, fc = u2 & 63;
        const float* src = Wo + (size_t)(fc * 8) * Oo + oo;          // Wo[f][o], stride Oo over f
#pragma unroll
        for (int j = 0; j < 8; ++j) o.h[j] = (half_t)src[(size_t)j * Oo];
        int fcs = (fc & ~7) | ((fc & 7) ^ (oo & 7));
        *(u32x4*)(WoT + (size_t)oo * Ff + fcs * 8) = o.u;
    }
}

// ---------------- fused QKV: one GEMM C[16384,1536] = X * Wcat^T (2-phase gload_lds) ----
// Shared mem is one flat 64KB array: A dbuf = S[0..16384), B dbuf = S[16384..32768).
// sel==2 (V) blocks reuse S after the main loop as a [128][136] f16 transpose scratch
// so Vt stores become fully coalesced 16B rows (was: 2B scatter at 4KB stride).
__global__ __launch_bounds__(256, 2) void k_qkv(const half_t* __restrict__ A,    // xh (swizzled)
                                                const half_t* __restrict__ Bw,   // Wcat (swizzled)
                                                half_t* __restrict__ Q,
                                                half_t* __restrict__ K,
                                                half_t* __restrict__ Vt) {
    __shared__ __attribute__((aligned(16))) half_t S[32768];   // 64 KB

    int bid = blockIdx.x;
    int virt = (bid & 7) * 192 + (bid >> 3);           // XCD x owns virt [x*192, x*192+192)
    int bm = virt / 12, bn = virt % 12;
    int m0 = bm * 128, n0 = bn * 128;

    int wave = threadIdx.x >> 6, lane = threadIdx.x & 63;
    int ar = lane & 15, kg = lane >> 4;
    int wm = wave >> 1, wn = wave & 1;
    int lr = lane >> 3, lc = lane & 7;                 // staging: row-in-seg, chunk

    f32x4 acc[4][4];
#pragma unroll
    for (int i = 0; i < 4; ++i)
#pragma unroll
        for (int j = 0; j < 4; ++j) acc[i][j] = (f32x4){0, 0, 0, 0};

#define STAGE_QKV(buf, kt)                                                                   \
    {                                                                                        \
        _Pragma("unroll")                                                                    \
        for (int i = 0; i < 4; ++i) {                                                        \
            int seg = wave * 4 + i;                                                          \
            int row = seg * 8 + lr;                                                          \
            gload16(A  + (size_t)(m0 + row) * Dd + (kt) * 64 + lc * 8,                       \
                    S + (buf) * 8192 + seg * 512);                                           \
            gload16(Bw + (size_t)(n0 + row) * Dd + (kt) * 64 + lc * 8,                       \
                    S + 16384 + (buf) * 8192 + seg * 512);                                   \
        }                                                                                    \
    }

    STAGE_QKV(0, 0);
    __syncthreads();
    int cur = 0;
    for (int kt = 0; kt < 8; ++kt) {
        if (kt < 7) STAGE_QKV(cur ^ 1, kt + 1);
        f16x8 bf[4][2];
#pragma unroll
        for (int n = 0; n < 4; ++n) {
            int row = wn * 64 + n * 16 + ar;
#pragma unroll
            for (int kh = 0; kh < 2; ++kh)
                bf[n][kh] = *(const f16x8*)&S[16384 + cur * 8192 + row * 64 + (((kg + kh * 4)) ^ (row & 7)) * 8];
        }
#pragma unroll
        for (int mi = 0; mi < 4; ++mi) {
            int row = wm * 64 + mi * 16 + ar;
            f16x8 a0 = *(const f16x8*)&S[cur * 8192 + row * 64 + ((kg)     ^ (row & 7)) * 8];
            f16x8 a1 = *(const f16x8*)&S[cur * 8192 + row * 64 + ((kg + 4) ^ (row & 7)) * 8];
#pragma unroll
            for (int n = 0; n < 4; ++n) {
                acc[mi][n] = __builtin_amdgcn_mfma_f32_16x16x32_f16(a0, bf[n][0], acc[mi][n], 0, 0, 0);
                acc[mi][n] = __builtin_amdgcn_mfma_f32_16x16x32_f16(a1, bf[n][1], acc[mi][n], 0, 0, 0);
            }
        }
        __syncthreads();
        cur ^= 1;
    }
    // epilogue: sel is block-uniform (N tiled 4/4/4 over Q,K,V)
    int sel = n0 >> 9;
    if (sel < 2) {
#pragma unroll
        for (int sn = 0; sn < 4; ++sn) {
            int nb = n0 + wn * 64 + sn * 16;
            int h = (nb >> 6) & 7, eb = nb & 63;
#pragma unroll
            for (int mi = 0; mi < 4; ++mi)
#pragma unroll
                for (int r = 0; r < 4; ++r) {
                    int sg = m0 + wm * 64 + mi * 16 + kg * 4 + r;
                    int bh = (sg >> 11) * 8 + h, sl = sg & 2047;
                    half_t val = (half_t)acc[mi][sn][r];
                    if (sel == 0) Q[((size_t)bh * Ss + sl) * Ee + eb + ar] = val;
                    else          K[((size_t)bh * Ss + sl) * Ee + eb + ar] = val;
                }
        }
    } else {
        // V: LDS transpose scratch [e_loc 0..127][s_loc 0..127], row pad to 136 halfs
        // (main loop ended with __syncthreads -> S is dead; 128*136 = 17408 <= 32768)
#pragma unroll
        for (int sn = 0; sn < 4; ++sn) {
            int e_loc = wn * 64 + sn * 16 + ar;
#pragma unroll
            for (int mi = 0; mi < 4; ++mi)
#pragma unroll
                for (int r = 0; r < 4; ++r) {
                    int s_loc = wm * 64 + mi * 16 + kg * 4 + r;
                    S[e_loc * 136 + s_loc] = (half_t)acc[mi][sn][r];
                }
        }
        __syncthreads();
        int b = m0 >> 11, sbase = m0 & 2047;
#pragma unroll
        for (int i = 0; i < 8; ++i) {
            int e_loc = wave * 32 + i * 4 + (lane >> 4);
            int chunk = lane & 15;
            f16x8 v = *(const f16x8*)&S[e_loc * 136 + chunk * 8];     // 272B row stride: 16B-aligned
            int h = ((n0 >> 6) + (e_loc >> 6)) & 7;
            int e_in = e_loc & 63;
            int bh = b * 8 + h;
            *(f16x8*)(Vt + ((size_t)bh * Ee + e_in) * Ss + sbase + chunk * 8) = v;   // coalesced
        }
    }
#undef STAGE_QKV
}

// ---------------- flash attention: swapped 32x32, KVBLK=64, merged-pair softmax --------
// (R13 proven version: 1024 blocks x 4 waves, 70.6 us)
__global__ __launch_bounds__(256, 4) void k_attn(const half_t* __restrict__ Q,
                                                 const half_t* __restrict__ Kg,
                                                 const half_t* __restrict__ Vtg,
                                                 half_t* __restrict__ ctx) {
    __shared__ __attribute__((aligned(16))) half_t Klds[2][64 * 64];   // 16 KB
    __shared__ __attribute__((aligned(16))) half_t Vlds[2][64 * 64];   // 16 KB

    int bid = blockIdx.x;                 // 0..1023
    int xcd = bid & 7;
    int idx = bid >> 3;                   // 0..127
    int g   = idx >> 3;                   // 0..15
    int g0 = g & 3, j = g >> 2;           // balanced qb permutation (per-CU sums 30)
    int qb;
    switch (j) {
        case 0:  qb = 15 - g0; break;
        case 1:  qb = 8 + (g0 ^ 2); break;
        case 2:  qb = 4 + g0; break;
        default: qb = g0 ^ 1; break;
    }
    int bh  = xcd * 8 + (idx & 7);        // 8 heads per XCD

    int wave = threadIdx.x >> 6, lane = threadIdx.x & 63;
    int ql = lane & 31, hi = lane >> 5;
    int qt32 = qb * 4 + wave;             // this wave's 32-row q-tile
    int qg = qt32 * 32 + ql;

    const half_t* Qb = Q   + (size_t)bh * Ss * Ee;
    const half_t* Kb = Kg  + (size_t)bh * Ss * Ee;
    const half_t* Vb = Vtg + (size_t)bh * Ee * Ss;

    // Q B-frags (persistent), pre-scaled by log2(e)
    const half_t* qp = Qb + (size_t)qg * Ee + hi * 8;
    f16x8 qf[4];
    const half_t l2e = (half_t)1.44269504f;
#pragma unroll
    for (int d = 0; d < 4; ++d) {
        qf[d] = *(const f16x8*)(qp + d * 16);
#pragma unroll
        for (int jj = 0; jj < 8; ++jj) qf[d][jj] *= l2e;
    }

    f32x16 ot0 = zero16(), ot1 = zero16();
    float m = -1e30f, lp = 0.f;

#define STAGE_KV(buf, kt64)                                                                 \
    {                                                                                       \
        _Pragma("unroll")                                                                   \
        for (int c = 0; c < 2; ++c) {                                                       \
            int seg = 2 * wave + c;                                                         \
            int tK = seg >> 2, dK = seg & 3;                                                \
            gload16(Kb + ((size_t)(kt64) * 64 + tK * 32 + ql) * Ee + dK * 16 + hi * 8,      \
                    &Klds[buf][seg * 512]);                                                 \
            int eh = (seg >> 1) & 1, d2 = seg & 1;                                          \
            gload16(Vb + (size_t)(eh * 32 + ql) * Ss + (kt64) * 64 + tK * 32 + d2 * 16 + hi * 8, \
                    &Vlds[buf][seg * 512]);                                                 \
        }                                                                                   \
    }

    STAGE_KV(0, 0);
    int cur = 0;
    int ktmax64 = qb * 2 + 1;             // block-common staging range (64-row tiles)
    for (int kt64 = 0; kt64 <= ktmax64; ++kt64) {
        __syncthreads();   // staged tile visible; prior reads of buf cur^1 done
        if (kt64 < ktmax64) STAGE_KV(cur ^ 1, kt64 + 1);
        int j0 = kt64 * 2;
        if (j0 <= qt32) {
            // ---- QK both sub-tiles (8 conflict-free ds_read_b128, 8 MFMA) ----
            f32x16 s0 = zero16(), s1 = zero16();
            {
                f16x8 ka0 = *(const f16x8*)&Klds[cur][lane * 8];
                f16x8 ka1 = *(const f16x8*)&Klds[cur][512 + lane * 8];
                f16x8 ka2 = *(const f16x8*)&Klds[cur][1024 + lane * 8];
                f16x8 ka3 = *(const f16x8*)&Klds[cur][1536 + lane * 8];
                __builtin_amdgcn_s_setprio(1);
                s0 = __builtin_amdgcn_mfma_f32_32x32x16_f16(ka0, qf[0], s0, 0, 0, 0);
                s0 = __builtin_amdgcn_mfma_f32_32x32x16_f16(ka1, qf[1], s0, 0, 0, 0);
                s0 = __builtin_amdgcn_mfma_f32_32x32x16_f16(ka2, qf[2], s0, 0, 0, 0);
                s0 = __builtin_amdgcn_mfma_f32_32x32x16_f16(ka3, qf[3], s0, 0, 0, 0);
                __builtin_amdgcn_s_setprio(0);
            }
            {
                f16x8 kb0 = *(const f16x8*)&Klds[cur][2048 + lane * 8];
                f16x8 kb1 = *(const f16x8*)&Klds[cur][2560 + lane * 8];
                f16x8 kb2 = *(const f16x8*)&Klds[cur][3072 + lane * 8];
                f16x8 kb3 = *(const f16x8*)&Klds[cur][3584 + lane * 8];
                __builtin_amdgcn_s_setprio(1);
                s1 = __builtin_amdgcn_mfma_f32_32x32x16_f16(kb0, qf[0], s1, 0, 0, 0);
                s1 = __builtin_amdgcn_mfma_f32_32x32x16_f16(kb1, qf[1], s1, 0, 0, 0);
                s1 = __builtin_amdgcn_mfma_f32_32x32x16_f16(kb2, qf[2], s1, 0, 0, 0);
                s1 = __builtin_amdgcn_mfma_f32_32x32x16_f16(kb3, qf[3], s1, 0, 0, 0);
                __builtin_amdgcn_s_setprio(0);
            }
            // ---- generalized causal mask (covers diagonal + overhanging sub-tile) ----
            if (j0 + 1 >= qt32) {
                int sh0 = (j0 - qt32) * 32;       // 0 when j0==qt32, -32 when j1==qt32
                int sh1 = sh0 + 32;
#pragma unroll
                for (int r = 0; r < 16; ++r) {
                    int kloc = (r & 3) + 8 * (r >> 2) + 4 * hi;
                    if (sh0 >= 0 && kloc + sh0 > ql) s0[r] = -1e30f;
                    if (kloc + sh1 > ql)             s1[r] = -1e30f;
                }
            }
            // ---- merged softmax over 32 score regs ----
            float mt = fmaxf(s0[0], s1[0]);
#pragma unroll
            for (int r = 1; r < 16; ++r) mt = fmaxf(mt, fmaxf(s0[r], s1[r]));
            mt = fmaxf(mt, __shfl_xor(mt, 32));
            if (!__all(mt <= m + 8.0f)) {      // T13 defer-max (one branch per pair)
                float mn = fmaxf(m, mt);
                float sc = exp2_fast(m - mn);
#pragma unroll
                for (int r = 0; r < 16; ++r) { ot0[r] *= sc; ot1[r] *= sc; }
                lp *= sc;
                m = mn;
            }
            float rs = 0.f;
#pragma unroll
            for (int r = 0; r < 16; ++r) { s0[r] = exp2_fast(s0[r] - m); rs += s0[r]; }
#pragma unroll
            for (int r = 0; r < 16; ++r) { s1[r] = exp2_fast(s1[r] - m); rs += s1[r]; }
            lp += rs;

            // ---- pack P (both sub-tiles) ----
            unsigned w0[8], w1[8];
#pragma unroll
            for (int mm = 0; mm < 8; ++mm) {
                asm("v_cvt_pkrtz_f16_f32 %0, %1, %2" : "=v"(w0[mm]) : "v"(s0[2 * mm]), "v"(s0[2 * mm + 1]));
                asm("v_cvt_pkrtz_f16_f32 %0, %1, %2" : "=v"(w1[mm]) : "v"(s1[2 * mm]), "v"(s1[2 * mm + 1]));
            }
            unsigned a0 = (unsigned)__shfl_xor((int)(hi ? w0[0] : w0[2]), 32);
            unsigned a1 = (unsigned)__shfl_xor((int)(hi ? w0[1] : w0[3]), 32);
            unsigned a2 = (unsigned)__shfl_xor((int)(hi ? w0[4] : w0[6]), 32);
            unsigned a3 = (unsigned)__shfl_xor((int)(hi ? w0[5] : w0[7]), 32);
            unsigned b0 = (unsigned)__shfl_xor((int)(hi ? w1[0] : w1[2]), 32);
            unsigned b1 = (unsigned)__shfl_xor((int)(hi ? w1[1] : w1[3]), 32);
            unsigned b2 = (unsigned)__shfl_xor((int)(hi ? w1[4] : w1[6]), 32);
            unsigned b3 = (unsigned)__shfl_xor((int)(hi ? w1[5] : w1[7]), 32);
            union { unsigned u[4]; f16x8 v; } pA0, pA1, pB0, pB1;
            pA0.u[0] = hi ? a0 : w0[0];  pA0.u[1] = hi ? a1 : w0[1];
            pA0.u[2] = hi ? w0[2] : a0;  pA0.u[3] = hi ? w0[3] : a1;
            pA1.u[0] = hi ? a2 : w0[4];  pA1.u[1] = hi ? a3 : w0[5];
            pA1.u[2] = hi ? w0[6] : a2;  pA1.u[3] = hi ? w0[7] : a3;
            pB0.u[0] = hi ? b0 : w1[0];  pB0.u[1] = hi ? b1 : w1[1];
            pB0.u[2] = hi ? w1[2] : b0;  pB0.u[3] = hi ? w1[3] : b1;
            pB1.u[0] = hi ? b2 : w1[4];  pB1.u[1] = hi ? b3 : w1[5];
            pB1.u[2] = hi ? w1[6] : b2;  pB1.u[3] = hi ? w1[7] : b3;

            // ---- PV both sub-tiles (8 conflict-free ds_read_b128, 8 MFMA) ----
            {
                f16x8 va0 = *(const f16x8*)&Vlds[cur][lane * 8];
                f16x8 va1 = *(const f16x8*)&Vlds[cur][512 + lane * 8];
                f16x8 va2 = *(const f16x8*)&Vlds[cur][1024 + lane * 8];
                f16x8 va3 = *(const f16x8*)&Vlds[cur][1536 + lane * 8];
                __builtin_amdgcn_s_setprio(1);
                ot0 = __builtin_amdgcn_mfma_f32_32x32x16_f16(va0, pA0.v, ot0, 0, 0, 0);
                ot0 = __builtin_amdgcn_mfma_f32_32x32x16_f16(va1, pA1.v, ot0, 0, 0, 0);
                ot1 = __builtin_amdgcn_mfma_f32_32x32x16_f16(va2, pA0.v, ot1, 0, 0, 0);
                ot1 = __builtin_amdgcn_mfma_f32_32x32x16_f16(va3, pA1.v, ot1, 0, 0, 0);
                __builtin_amdgcn_s_setprio(0);
            }
            {
                f16x8 vb0 = *(const f16x8*)&Vlds[cur][2048 + lane * 8];
                f16x8 vb1 = *(const f16x8*)&Vlds[cur][2560 + lane * 8];
                f16x8 vb2 = *(const f16x8*)&Vlds[cur][3072 + lane * 8];
                f16x8 vb3 = *(const f16x8*)&Vlds[cur][3584 + lane * 8];
                __builtin_amdgcn_s_setprio(1);
                ot0 = __builtin_amdgcn_mfma_f32_32x32x16_f16(vb0, pB0.v, ot0, 0, 0, 0);
                ot0 = __builtin_amdgcn_mfma_f32_32x32x16_f16(vb1, pB1.v, ot0, 0, 0, 0);
                ot1 = __builtin_amdgcn_mfma_f32_32x32x16_f16(vb2, pB0.v, ot1, 0, 0, 0);
                ot1 = __builtin_amdgcn_mfma_f32_32x32x16_f16(vb3, pB1.v, ot1, 0, 0, 0);
                __builtin_amdgcn_s_setprio(0);
            }
        }
        cur ^= 1;
    }
#undef STAGE_KV

    float lf = lp + __shfl_xor(lp, 32);
    float inv = 1.0f / lf;
    int b = bh >> 3, h = bh & 7;
    int qs = qg & 7;
    half_t* cb = ctx + ((size_t)b * Ss + qg) * Ff;
#pragma unroll
    for (int gg = 0; gg < 4; ++gg) {
        h16x4 v0, v1;
#pragma unroll
        for (int jj = 0; jj < 4; ++jj) {
            v0[jj] = (half_t)(ot0[gg * 4 + jj] * inv);
            v1[jj] = (half_t)(ot1[gg * 4 + jj] * inv);
        }
        *(h16x4*)(cb + (h * 8 + (gg ^ qs)) * 8 + 4 * hi)       = v0;
        *(h16x4*)(cb + (h * 8 + ((gg + 4) ^ qs)) * 8 + 4 * hi) = v1;
    }
}

// ---------------- output projection: same 2-phase GEMM, C[16384,512] f32 ----------------
__global__ __launch_bounds__(256, 2) void k_proj(const half_t* __restrict__ A,    // ctx (swizzled)
                                                 const half_t* __restrict__ Bw,   // WoT (swizzled)
                                                 float* __restrict__ out) {
    __shared__ __attribute__((aligned(16))) half_t Ab[2][128 * 64];
    __shared__ __attribute__((aligned(16))) half_t Bbuf[2][128 * 64];

    int bid = blockIdx.x;
    int virt = (bid & 7) * 64 + (bid >> 3);
    int bm = virt >> 2, bn = virt & 3;
    int m0 = bm * 128, n0 = bn * 128;

    int wave = threadIdx.x >> 6, lane = threadIdx.x & 63;
    int ar = lane & 15, kg = lane >> 4;
    int wm = wave >> 1, wn = wave & 1;
    int lr = lane >> 3, lc = lane & 7;

    f32x4 acc[4][4];
#pragma unroll
    for (int i = 0; i < 4; ++i)
#pragma unroll
        for (int j = 0; j < 4; ++j) acc[i][j] = (f32x4){0, 0, 0, 0};

#define STAGE_PRJ(buf, kt)                                                              \
    {                                                                                   \
        _Pragma("unroll")                                                               \
        for (int i = 0; i < 4; ++i) {                                                   \
            int seg = wave * 4 + i;                                                     \
            int row = seg * 8 + lr;                                                     \
            gload16(A  + (size_t)(m0 + row) * Ff + (kt) * 64 + lc * 8, &Ab[buf][seg * 512]);   \
            gload16(Bw + (size_t)(n0 + row) * Ff + (kt) * 64 + lc * 8, &Bbuf[buf][seg * 512]); \
        }                                                                               \
    }

    STAGE_PRJ(0, 0);
    __syncthreads();
    int cur = 0;
    for (int kt = 0; kt < 8; ++kt) {
        if (kt < 7) STAGE_PRJ(cur ^ 1, kt + 1);
        f16x8 bf[4][2];
#pragma unroll
        for (int n = 0; n < 4; ++n) {
            int row = wn * 64 + n * 16 + ar;
#pragma unroll
            for (int kh = 0; kh < 2; ++kh)
                bf[n][kh] = *(const f16x8*)&Bbuf[cur][row * 64 + (((kg + kh * 4)) ^ (row & 7)) * 8];
        }
#pragma unroll
        for (int mi = 0; mi < 4; ++mi) {
            int row = wm * 64 + mi * 16 + ar;
            f16x8 a0 = *(const f16x8*)&Ab[cur][row * 64 + ((kg)     ^ (row & 7)) * 8];
            f16x8 a1 = *(const f16x8*)&Ab[cur][row * 64 + ((kg + 4) ^ (row & 7)) * 8];
#pragma unroll
            for (int n = 0; n < 4; ++n) {
                acc[mi][n] = __builtin_amdgcn_mfma_f32_16x16x32_f16(a0, bf[n][0], acc[mi][n], 0, 0, 0);
                acc[mi][n] = __builtin_amdgcn_mfma_f32_16x16x32_f16(a1, bf[n][1], acc[mi][n], 0, 0, 0);
            }
        }
        __syncthreads();
        cur ^= 1;
    }
#pragma unroll
    for (int sn = 0; sn < 4; ++sn)
#pragma unroll
        for (int mi = 0; mi < 4; ++mi)
#pragma unroll
            for (int r = 0; r < 4; ++r) {
                int sg = m0 + wm * 64 + mi * 16 + kg * 4 + r;
                out[(size_t)sg * Oo + n0 + wn * 64 + sn * 16 + ar] = acc[mi][sn][r];
            }
#undef STAGE_PRJ
}

extern "C" void kernel_launch(void* const* d_in, const int* in_sizes, int n_in,
                              void* d_out, int out_size, void* d_ws, size_t ws_size,
                              hipStream_t stream) {
    const float* x  = (const float*)d_in[0];
    const float* Wq = (const float*)d_in[1];
    const float* Wk = (const float*)d_in[2];
    const float* Wv = (const float*)d_in[3];
    const float* Wo = (const float*)d_in[4];
    float* out = (float*)d_out;

    // workspace (all f16, fully rewritten every call): ~82 MB
    char* ws = (char*)d_ws;
    size_t off = 0;
    half_t* xh   = (half_t*)(ws + off); off += (size_t)Bb * Ss * Dd * 2;      // swizzled
    half_t* Wcat = (half_t*)(ws + off); off += (size_t)Ncat * Dd * 2;         // swizzled
    half_t* WoT  = (half_t*)(ws + off); off += (size_t)Oo * Ff * 2;           // swizzled
    half_t* Qd   = (half_t*)(ws + off); off += (size_t)Bb * Hh * Ss * Ee * 2; // plain [bh][s][e]
    half_t* Kd   = (half_t*)(ws + off); off += (size_t)Bb * Hh * Ss * Ee * 2; // plain [bh][s][e]
    half_t* Vtd  = (half_t*)(ws + off); off += (size_t)Bb * Hh * Ss * Ee * 2; // plain [bh][e][s]
    half_t* ctx  = (half_t*)(ws + off); off += (size_t)Bb * Ss * Ff * 2;      // swizzled

    k_cvt_x<<<4096, 256, 0, stream>>>(x, xh);
    k_cvt_w<<<512, 256, 0, stream>>>(Wq, Wk, Wv, Wo, Wcat, WoT);
    k_qkv<<<1536, 256, 0, stream>>>(xh, Wcat, Qd, Kd, Vtd);
    k_attn<<<1024, 256, 0, stream>>>(Qd, Kd, Vtd, ctx);
    k_proj<<<512, 256, 0, stream>>>(ctx, WoT, out);
}